// Round 8
// baseline (521.634 us; speedup 1.0000x reference)
//
#include <hip/hip_runtime.h>
#include <hip/hip_bf16.h>
#include <cmath>

#define TT 1024
#define HH 1024
#define FF 768
#define EE 32
#define MAXT2 64    // sum_e ceil(n_e/128) <= 4096/128 + 32 = 64

typedef __bf16 bf16;
typedef __bf16 v4bf __attribute__((ext_vector_type(4)));
typedef __bf16 v8bf __attribute__((ext_vector_type(8)));
typedef float  v4f  __attribute__((ext_vector_type(4)));

static __device__ __forceinline__ v4f mfma16(v8bf a, v8bf b, v4f c) {
    return __builtin_amdgcn_mfma_f32_16x16x32_bf16(a, b, c, 0, 0, 0);
}

// ---------------------------------------------------------------- router
// 1 wave per token. fp64 dot so top-k selection matches the high-precision
// reference. Top-k on LOGITS (exp monotone); softmax denom cancels under
// renormalization, so only the 4 kept exps are computed.
__global__ __launch_bounds__(64) void router_k(
    const float* __restrict__ x, const float* __restrict__ gw,
    bf16* __restrict__ xbf, int* __restrict__ tk_id, float* __restrict__ tk_w)
{
    int t = blockIdx.x, lane = threadIdx.x;
    float4 xr[4];
    const float4* xrow = (const float4*)(x + (size_t)t * HH);
#pragma unroll
    for (int i = 0; i < 4; ++i) xr[i] = xrow[i * 64 + lane];
#pragma unroll
    for (int i = 0; i < 4; ++i) {
        v4bf b = { (bf16)xr[i].x, (bf16)xr[i].y, (bf16)xr[i].z, (bf16)xr[i].w };
        *(v4bf*)(xbf + (size_t)t * HH + (i * 64 + lane) * 4) = b;
    }

    double acc[EE];
#pragma unroll
    for (int e = 0; e < EE; ++e) {
        const float4* grow = (const float4*)(gw + (size_t)e * HH);
        double a = 0.0;
#pragma unroll
        for (int i = 0; i < 4; ++i) {
            float4 g = grow[i * 64 + lane];
            a += (double)xr[i].x * g.x + (double)xr[i].y * g.y
               + (double)xr[i].z * g.z + (double)xr[i].w * g.w;
        }
        acc[e] = a;
    }
#pragma unroll
    for (int m = 1; m < 64; m <<= 1) {
#pragma unroll
        for (int e = 0; e < EE; ++e) acc[e] += __shfl_xor(acc[e], m, 64);
    }
    if (lane == 0) {
        int ids[4]; double lv[4];
        for (int k = 0; k < 4; ++k) {
            int best = 0; double bv = -1.0e300;
            for (int e = 0; e < EE; ++e)
                if (acc[e] > bv) { bv = acc[e]; best = e; }
            ids[k] = best; lv[k] = bv; acc[best] = -2.0e300;
        }
        double w[4], s = 0.0;
        for (int k = 0; k < 4; ++k) { w[k] = exp(lv[k] - lv[0]); s += w[k]; }
        for (int k = 0; k < 4; ++k) {
            tk_id[t * 4 + k] = ids[k];
            tk_w[t * 4 + k] = (float)(w[k] / s);
        }
    }
}

// ---------------------------------------------------------------- scatter
// Single block: count -> scan -> compact (token*4+k, weight) + 128-row
// (expert, m-tile) work list consumed by both GEMMs.
__global__ __launch_bounds__(1024) void scatter_k(
    const int* __restrict__ tk_id, const float* __restrict__ tk_w,
    int* __restrict__ cnt, int* __restrict__ offs,
    int* __restrict__ list, float* __restrict__ wlist,
    int* __restrict__ tile_e, int* __restrict__ tile_m)
{
    __shared__ int c_s[EE], o_s[EE], cur_s[EE];
    int tid = threadIdx.x;
    if (tid < EE) { c_s[tid] = 0; cur_s[tid] = 0; }
    __syncthreads();
    int ids[4]; float w[4];
#pragma unroll
    for (int k = 0; k < 4; ++k) { ids[k] = tk_id[tid * 4 + k]; w[k] = tk_w[tid * 4 + k]; }
#pragma unroll
    for (int k = 0; k < 4; ++k) atomicAdd(&c_s[ids[k]], 1);
    __syncthreads();
    if (tid == 0) {
        int a = 0;
        for (int e = 0; e < EE; ++e) { o_s[e] = a; a += c_s[e]; }
        int nt = 0;
        for (int e = 0; e < EE; ++e)
            for (int m = 0; m * 128 < c_s[e]; ++m) { tile_e[nt] = e; tile_m[nt] = m; ++nt; }
        for (int i = nt; i < MAXT2; ++i) { tile_e[i] = -1; tile_m[i] = 0; }
    }
    __syncthreads();
#pragma unroll
    for (int k = 0; k < 4; ++k) {
        int e = ids[k];
        int pos = atomicAdd(&cur_s[e], 1);
        int idx = o_s[e] + pos;
        list[idx] = tid * 4 + k;
        wlist[idx] = w[k];
    }
    if (tid < EE) { cnt[tid] = c_s[tid]; offs[tid] = o_s[tid]; }
    if (tid >= 1024 - 128) {                // pad 128 tail entries for 128-row tiles
        list[4096 + (tid - 896)] = 0;
        wlist[4096 + (tid - 896)] = 0.f;
    }
}

// ---------------------------------------------------------------- gemm1 + silu
// grid 1536 = 64 tiles x 24 f-blocks (32 g + 32 u rows each), XCD swizzle.
// Tile 128 tokens x 32 f-pairs, K=1024 step 64. Per thread: 64B-contiguous
// B reads (4 x float4), A gathered bf16. 16 MFMA/iter/wave for 32KB staged.
__global__ __launch_bounds__(256) void gemm1_k(
    const bf16* __restrict__ xbf, const float* __restrict__ w1,
    const int* __restrict__ cnt, const int* __restrict__ offs,
    const int* __restrict__ list, const int* __restrict__ tile_e,
    const int* __restrict__ tile_m, bf16* __restrict__ act)
{
    int id = blockIdx.x;                    // 0..1535
    int p = (id & 7) * 192 + (id >> 3);     // bijective XCD-chunked swizzle
    int fb = p >> 6, tl = p & 63;           // fb 0..23, tl 0..63
    int e = tile_e[tl];
    if (e < 0) return;
    int mt = tile_m[tl];
    int n = cnt[e];
    int base = offs[e];

    __shared__ bf16 As[128][72];            // 18.4 KB
    __shared__ bf16 Bs[64][72];             //  9.2 KB (rows 0..31 g, 32..63 u)

    int tid = threadIdx.x;
    int wid = tid >> 6, lane = tid & 63;
    int wr = wid >> 1, wc = wid & 1;
    int lrow = lane & 15, lk = (lane >> 4) * 8;
    const float* w1e = w1 + (size_t)e * 1536 * HH;

    // A staging: 2 threads per row, 64B (4 x v8bf) each
    int arow = tid >> 1, ahalf = (tid & 1) * 32;
    const bf16* aptr = xbf + (size_t)(list[base + mt * 128 + arow] >> 2) * HH + ahalf;
    // B staging: 4 threads per row, 64B (4 x float4) each, contiguous
    int brow = tid >> 2, bq = (tid & 3) * 16;
    int grow = (brow < 32) ? (fb * 32 + brow) : (FF + fb * 32 + (brow - 32));
    const float* bptr = w1e + (size_t)grow * HH + bq;

    v4f accg[4], accu[4];
#pragma unroll
    for (int m = 0; m < 4; ++m) { accg[m] = (v4f)0.f; accu[m] = (v4f)0.f; }

    for (int k0 = 0; k0 < HH; k0 += 64) {
#pragma unroll
        for (int q = 0; q < 4; ++q)
            *(v8bf*)&As[arow][ahalf + q * 8] = *(const v8bf*)(aptr + k0 + q * 8);
        float4 f0 = *(const float4*)(bptr + k0);
        float4 f1 = *(const float4*)(bptr + k0 + 4);
        float4 f2 = *(const float4*)(bptr + k0 + 8);
        float4 f3 = *(const float4*)(bptr + k0 + 12);
        v8bf p0 = { (bf16)f0.x, (bf16)f0.y, (bf16)f0.z, (bf16)f0.w,
                    (bf16)f1.x, (bf16)f1.y, (bf16)f1.z, (bf16)f1.w };
        v8bf p1 = { (bf16)f2.x, (bf16)f2.y, (bf16)f2.z, (bf16)f2.w,
                    (bf16)f3.x, (bf16)f3.y, (bf16)f3.z, (bf16)f3.w };
        *(v8bf*)&Bs[brow][bq] = p0;
        *(v8bf*)&Bs[brow][bq + 8] = p1;
        __syncthreads();
#pragma unroll
        for (int ks = 0; ks < 2; ++ks) {
            int kk = ks * 32 + lk;
            v8bf bg = *(const v8bf*)&Bs[wc * 16 + lrow][kk];
            v8bf bu = *(const v8bf*)&Bs[32 + wc * 16 + lrow][kk];
#pragma unroll
            for (int mi = 0; mi < 4; ++mi) {
                v8bf a = *(const v8bf*)&As[wr * 64 + mi * 16 + lrow][kk];
                accg[mi] = mfma16(a, bg, accg[mi]);
                accu[mi] = mfma16(a, bu, accu[mi]);
            }
        }
        __syncthreads();
    }
    // epilogue: act = silu(g) * u
    int rsub = (lane >> 4) * 4;
    int col = fb * 32 + wc * 16 + lrow;
#pragma unroll
    for (int mi = 0; mi < 4; ++mi)
#pragma unroll
        for (int j = 0; j < 4; ++j) {
            int r = mt * 128 + wr * 64 + mi * 16 + rsub + j;
            if (r < n) {
                float g = accg[mi][j], u = accu[mi][j];
                float a = g / (1.f + __expf(-g)) * u;
                act[(size_t)(base + r) * FF + col] = (bf16)a;
            }
        }
}

// ---------------------------------------------------------------- gemm2
// grid 1024 = 64 tiles x 16 h-blocks, XCD swizzle. Tile 128 slots x 64 h,
// K=768 step 64. Scales rows by routing weight, writes per-slot fp32 rows.
__global__ __launch_bounds__(256) void gemm2_k(
    const bf16* __restrict__ act, const float* __restrict__ w2,
    const int* __restrict__ cnt, const int* __restrict__ offs,
    const int* __restrict__ list, const float* __restrict__ wlist,
    const int* __restrict__ tile_e, const int* __restrict__ tile_m,
    float* __restrict__ ybuf)
{
    int id = blockIdx.x;                    // 0..1023
    int p = (id & 7) * 128 + (id >> 3);
    int hb = p >> 6, tl = p & 63;           // hb 0..15, tl 0..63
    int e = tile_e[tl];
    if (e < 0) return;
    int mt = tile_m[tl];
    int n = cnt[e];
    int base = offs[e];

    __shared__ bf16 As[128][72];
    __shared__ bf16 Bs[64][72];

    int tid = threadIdx.x;
    int wid = tid >> 6, lane = tid & 63;
    int wr = wid >> 1, wc = wid & 1;
    int lrow = lane & 15, lk = (lane >> 4) * 8;
    const float* w2e = w2 + (size_t)e * HH * FF;

    int arow = tid >> 1, ahalf = (tid & 1) * 32;
    const bf16* aptr = act + (size_t)(base + mt * 128 + arow) * FF + ahalf;
    int brow = tid >> 2, bq = (tid & 3) * 16;
    const float* bptr = w2e + (size_t)(hb * 64 + brow) * FF + bq;

    v4f acc[4][2];
#pragma unroll
    for (int m = 0; m < 4; ++m)
#pragma unroll
        for (int nf = 0; nf < 2; ++nf) acc[m][nf] = (v4f)0.f;

    for (int k0 = 0; k0 < FF; k0 += 64) {
#pragma unroll
        for (int q = 0; q < 4; ++q)
            *(v8bf*)&As[arow][ahalf + q * 8] = *(const v8bf*)(aptr + k0 + q * 8);
        float4 f0 = *(const float4*)(bptr + k0);
        float4 f1 = *(const float4*)(bptr + k0 + 4);
        float4 f2 = *(const float4*)(bptr + k0 + 8);
        float4 f3 = *(const float4*)(bptr + k0 + 12);
        v8bf p0 = { (bf16)f0.x, (bf16)f0.y, (bf16)f0.z, (bf16)f0.w,
                    (bf16)f1.x, (bf16)f1.y, (bf16)f1.z, (bf16)f1.w };
        v8bf p1 = { (bf16)f2.x, (bf16)f2.y, (bf16)f2.z, (bf16)f2.w,
                    (bf16)f3.x, (bf16)f3.y, (bf16)f3.z, (bf16)f3.w };
        *(v8bf*)&Bs[brow][bq] = p0;
        *(v8bf*)&Bs[brow][bq + 8] = p1;
        __syncthreads();
#pragma unroll
        for (int ks = 0; ks < 2; ++ks) {
            int kk = ks * 32 + lk;
            v8bf b0 = *(const v8bf*)&Bs[wc * 32 + lrow][kk];
            v8bf b1 = *(const v8bf*)&Bs[wc * 32 + 16 + lrow][kk];
#pragma unroll
            for (int mi = 0; mi < 4; ++mi) {
                v8bf a = *(const v8bf*)&As[wr * 64 + mi * 16 + lrow][kk];
                acc[mi][0] = mfma16(a, b0, acc[mi][0]);
                acc[mi][1] = mfma16(a, b1, acc[mi][1]);
            }
        }
        __syncthreads();
    }
    int rsub = (lane >> 4) * 4;
#pragma unroll
    for (int mi = 0; mi < 4; ++mi)
#pragma unroll
        for (int j = 0; j < 4; ++j) {
            int r = mt * 128 + wr * 64 + mi * 16 + rsub + j;
            if (r < n) {
                int code = list[base + r];
                float w = wlist[base + r];
#pragma unroll
                for (int nf = 0; nf < 2; ++nf) {
                    int col = hb * 64 + wc * 32 + nf * 16 + lrow;
                    ybuf[(size_t)code * HH + col] = acc[mi][nf][j] * w;
                }
            }
        }
}

// ---------------------------------------------------------------- combine
__global__ __launch_bounds__(256) void combine_k(
    const float* __restrict__ ybuf, float* __restrict__ out)
{
    int idx = blockIdx.x * 256 + threadIdx.x;   // float4 index
    int t = idx >> 8, c = idx & 255;
    const float4* yb = (const float4*)ybuf;
    float4 a = yb[(size_t)(t * 4 + 0) * 256 + c];
    float4 b = yb[(size_t)(t * 4 + 1) * 256 + c];
    float4 d = yb[(size_t)(t * 4 + 2) * 256 + c];
    float4 e = yb[(size_t)(t * 4 + 3) * 256 + c];
    float4 s;
    s.x = a.x + b.x + d.x + e.x;
    s.y = a.y + b.y + d.y + e.y;
    s.z = a.z + b.z + d.z + e.z;
    s.w = a.w + b.w + d.w + e.w;
    ((float4*)out)[(size_t)t * 256 + c] = s;
}

// ---------------------------------------------------------------- launch
extern "C" void kernel_launch(void* const* d_in, const int* in_sizes, int n_in,
                              void* d_out, int out_size, void* d_ws, size_t ws_size,
                              hipStream_t stream)
{
    const float* x  = (const float*)d_in[0];
    const float* gw = (const float*)d_in[1];
    const float* w1 = (const float*)d_in[2];
    const float* w2 = (const float*)d_in[3];
    float* out = (float*)d_out;

    char* ws = (char*)d_ws;
    size_t off = 0;
    auto alloc = [&](size_t bytes) {
        void* p = ws + off;
        off = (off + bytes + 255) & ~(size_t)255;
        return p;
    };
    bf16*  xbf    = (bf16*) alloc((size_t)TT * HH * 2);
    int*   tk_id  = (int*)  alloc(4096 * 4);
    float* tk_w   = (float*)alloc(4096 * 4);
    int*   cnt    = (int*)  alloc(EE * 4);
    int*   offs   = (int*)  alloc(EE * 4);
    int*   list   = (int*)  alloc(4224 * 4);
    float* wlist  = (float*)alloc(4224 * 4);
    int*   tile_e = (int*)  alloc(MAXT2 * 4);
    int*   tile_m = (int*)  alloc(MAXT2 * 4);
    bf16*  act    = (bf16*) alloc((size_t)4224 * FF * 2);
    float* ybuf   = (float*)alloc((size_t)4096 * HH * 4);

    router_k<<<TT, 64, 0, stream>>>(x, gw, xbf, tk_id, tk_w);
    scatter_k<<<1, 1024, 0, stream>>>(tk_id, tk_w, cnt, offs, list, wlist, tile_e, tile_m);
    gemm1_k<<<1536, 256, 0, stream>>>(xbf, w1, cnt, offs, list, tile_e, tile_m, act);
    gemm2_k<<<1024, 256, 0, stream>>>(act, w2, cnt, offs, list, wlist, tile_e, tile_m, ybuf);
    combine_k<<<1024, 256, 0, stream>>>(ybuf, out);
}